// Round 2
// baseline (5981.273 us; speedup 1.0000x reference)
//
#include <hip/hip_runtime.h>
#include <hip/hip_bf16.h>

#define EPSV 1e-5f
#define GR 64

// ---------------- storage type traits ----------------

struct F8 { unsigned char v; };  // OCP e4m3fn, manual codec (emergency low-mem tier)

static __device__ __forceinline__ float e4m3_dec(unsigned char b) {
    int s = b >> 7, E = (b >> 3) & 15, m = b & 7;
    float v = (E == 0) ? (float)m * 0.001953125f
                       : (float)(8 + m) * 0.125f * exp2f((float)(E - 7));
    return s ? -v : v;
}
static __device__ __forceinline__ unsigned char e4m3_enc(float f) {
    unsigned su = (__float_as_uint(f) >> 24) & 0x80u;
    float a = fabsf(f);
    if (!(a < 448.f)) return (unsigned char)(su | 0x7E);  // saturate (covers inf/nan-ish)
    if (a < 0.015625f) {                                   // subnormal: step 2^-9
        int m = (int)rintf(a * 512.f);
        return (unsigned char)(su | (m >= 8 ? 0x08 : m));
    }
    int e;
    frexpf(a, &e);                                         // a = f*2^e, f in [0.5,1)
    int E = e - 1 + 7;
    float mant = a * exp2f((float)(1 - e)) - 1.0f;         // [0,1)
    int mi = (int)rintf(mant * 8.f);
    if (mi >= 8) { mi = 0; E++; }
    if (E >= 16) return (unsigned char)(su | 0x7E);
    if (E == 15 && mi == 7) mi = 6;                        // avoid NaN encoding
    return (unsigned char)(su | (E << 3) | mi);
}

template <typename T> struct IO;
template <> struct IO<float> {
    static __device__ __forceinline__ float ld(const float* p) { return *p; }
    static __device__ __forceinline__ void st(float* p, float v) { *p = v; }
};
template <> struct IO<__hip_bfloat16> {
    static __device__ __forceinline__ float ld(const __hip_bfloat16* p) { return __bfloat162float(*p); }
    static __device__ __forceinline__ void st(__hip_bfloat16* p, float v) { *p = __float2bfloat16(v); }
};
template <> struct IO<F8> {
    static __device__ __forceinline__ float ld(const F8* p) { return e4m3_dec(p->v); }
    static __device__ __forceinline__ void st(F8* p, float v) { p->v = e4m3_enc(v); }
};

// ---------------- graph setup ----------------

__global__ void k_count(const int* __restrict__ dst, int* __restrict__ cnt, int E) {
    int e = blockIdx.x * blockDim.x + threadIdx.x;
    if (e < E) atomicAdd(&cnt[dst[e]], 1);
}

__global__ void k_dinv(const int* __restrict__ cnt, float* __restrict__ dinv, int N) {
    int i = blockIdx.x * blockDim.x + threadIdx.x;
    if (i < N) dinv[i] = rsqrtf((float)(cnt[i] + 1));  // +1 self loop, deg>0 always
}

__global__ void k_scan1(const int* __restrict__ cnt, int* __restrict__ bsum, int N) {
    __shared__ int s[256];
    int i = blockIdx.x * 256 + threadIdx.x;
    s[threadIdx.x] = (i < N) ? cnt[i] : 0;
    __syncthreads();
    for (int o = 128; o > 0; o >>= 1) {
        if (threadIdx.x < o) s[threadIdx.x] += s[threadIdx.x + o];
        __syncthreads();
    }
    if (threadIdx.x == 0) bsum[blockIdx.x] = s[0];
}

__global__ void k_scan2(int* __restrict__ bsum, int B) {  // 1 block, 1024 thr, excl scan
    __shared__ int s[1024];
    int t = threadIdx.x;
    int orig = (t < B) ? bsum[t] : 0;
    s[t] = orig;
    __syncthreads();
    for (int o = 1; o < 1024; o <<= 1) {
        int v = (t >= o) ? s[t - o] : 0;
        __syncthreads();
        s[t] += v;
        __syncthreads();
    }
    if (t < B) bsum[t] = s[t] - orig;
}

__global__ void k_scan3(const int* __restrict__ cnt, const int* __restrict__ bsum,
                        int* __restrict__ roff, int* __restrict__ cursor, int N) {
    __shared__ int s[256];
    int i = blockIdx.x * 256 + threadIdx.x;
    int v = (i < N) ? cnt[i] : 0;
    s[threadIdx.x] = v;
    __syncthreads();
    for (int o = 1; o < 256; o <<= 1) {
        int u = (threadIdx.x >= o) ? s[threadIdx.x - o] : 0;
        __syncthreads();
        s[threadIdx.x] += u;
        __syncthreads();
    }
    if (i < N) {
        int off = bsum[blockIdx.x] + s[threadIdx.x] - v;  // exclusive
        roff[i] = off;
        cursor[i] = off;
        if (i == N - 1) roff[N] = off + v;
    }
}

__global__ void k_scatter(const int* __restrict__ src, const int* __restrict__ dst,
                          const float* __restrict__ dinv, int* __restrict__ cursor,
                          int* __restrict__ col, float* __restrict__ val, int E) {
    int e = blockIdx.x * blockDim.x + threadIdx.x;
    if (e < E) {
        int s = src[e], d = dst[e];
        int p = atomicAdd(&cursor[d], 1);
        col[p] = s;
        val[p] = dinv[s] * dinv[d];
    }
}

// ---------------- sparse ops ----------------

// A @ x with 3 features (layer-0 reorder: (A@x)@W0)
__global__ void k_spmm3(const float* __restrict__ X, const int* __restrict__ col,
                        const float* __restrict__ val, const int* __restrict__ roff,
                        const float* __restrict__ dinv, float* __restrict__ XA, int N) {
    int i = blockIdx.x * blockDim.x + threadIdx.x;
    if (i >= N) return;
    float di = dinv[i];
    float w0 = di * di;
    float a0 = X[(size_t)i * 3 + 0] * w0;
    float a1 = X[(size_t)i * 3 + 1] * w0;
    float a2 = X[(size_t)i * 3 + 2] * w0;
    int je = roff[i + 1];
    for (int j = roff[i]; j < je; j++) {
        int s = col[j];
        float w = val[j];
        a0 += X[(size_t)s * 3 + 0] * w;
        a1 += X[(size_t)s * 3 + 1] * w;
        a2 += X[(size_t)s * 3 + 2] * w;
    }
    XA[(size_t)i * 3 + 0] = a0;
    XA[(size_t)i * 3 + 1] = a1;
    XA[(size_t)i * 3 + 2] = a2;
}

// A @ H (H bf16), 128 features: one block (128 thr) per row, coalesced row gathers
template <typename ZT>
__global__ __launch_bounds__(128) void k_spmm128(
    const __hip_bfloat16* __restrict__ H, const int* __restrict__ col,
    const float* __restrict__ val, const int* __restrict__ roff,
    const float* __restrict__ dinv, ZT* __restrict__ Y, int N) {
    int i = blockIdx.x;
    int c = threadIdx.x;
    float di = dinv[i];
    float acc = __bfloat162float(H[(size_t)i * 128 + c]) * di * di;
    int jb = roff[i], je = roff[i + 1];
    for (int j = jb; j < je; j++) {
        int s = col[j];
        float w = val[j];
        acc += __bfloat162float(H[(size_t)s * 128 + c]) * w;
    }
    IO<ZT>::st(&Y[(size_t)i * 128 + c], acc);
}

// A @ t, 1 feature, fused sigmoid -> final output
__global__ void k_spmm1(const float* __restrict__ T, const int* __restrict__ col,
                        const float* __restrict__ val, const int* __restrict__ roff,
                        const float* __restrict__ dinv, float* __restrict__ out, int N) {
    int i = blockIdx.x * blockDim.x + threadIdx.x;
    if (i >= N) return;
    float di = dinv[i];
    float a = T[i] * di * di;
    int je = roff[i + 1];
    for (int j = roff[i]; j < je; j++) a += T[col[j]] * val[j];
    out[i] = 1.0f / (1.0f + expf(-a));
}

// ---------------- dense ops ----------------

// y0 = XA @ W0, K=3
template <typename ZT>
__global__ void k_gemm3(const float* __restrict__ XA, const float* __restrict__ W0,
                        ZT* __restrict__ Y, int N) {
    int idx = blockIdx.x * blockDim.x + threadIdx.x;
    if (idx >= N * 128) return;
    int i = idx >> 7, c = idx & 127;
    float v = XA[(size_t)i * 3 + 0] * W0[c] + XA[(size_t)i * 3 + 1] * W0[128 + c] +
              XA[(size_t)i * 3 + 2] * W0[256 + c];
    IO<ZT>::st(&Y[idx], v);
}

// H(bf16) = (Z [+ skip]) @ W  -- 64-row tile, k-chunked W in LDS
template <typename ZT, typename XT>
__global__ __launch_bounds__(256) void k_gemm128(
    const ZT* __restrict__ Z, const XT* __restrict__ skip,
    const float* __restrict__ W, __hip_bfloat16* __restrict__ H, int N) {
    __shared__ float sZ[GR * 132];   // padded stride 132
    __shared__ float sW[32 * 128];   // k-chunk of W
    int tid = threadIdx.x;
    int row0 = blockIdx.x * GR;

    // stage Z rows (+ optional skip add)
    for (int t = tid; t < GR * 128; t += 256) {
        int r = t >> 7, c = t & 127;
        int grow = row0 + r;
        float v = 0.f;
        if (grow < N) {
            v = IO<ZT>::ld(&Z[(size_t)grow * 128 + c]);
            if (skip) v += IO<XT>::ld(&skip[(size_t)grow * 128 + c]);
        }
        sZ[r * 132 + c] = v;
    }

    int tc = tid & 15;   // col lane: cols c = tc + 16*cc
    int tr = tid >> 4;   // row group: rows r0..r0+3
    int r0 = tr * 4;
    float acc[4][8];
#pragma unroll
    for (int r = 0; r < 4; r++)
#pragma unroll
        for (int cc = 0; cc < 8; cc++) acc[r][cc] = 0.f;

    for (int k0 = 0; k0 < 128; k0 += 32) {
        __syncthreads();
        // stage W[k0:k0+32][:]  (4096 floats = 1024 float4)
        for (int t = tid; t < 1024; t += 256)
            ((float4*)sW)[t] = ((const float4*)(W + k0 * 128))[t];
        __syncthreads();
#pragma unroll 4
        for (int k = 0; k < 32; k++) {
            float zr[4];
#pragma unroll
            for (int r = 0; r < 4; r++) zr[r] = sZ[(r0 + r) * 132 + k0 + k];
            float wv[8];
#pragma unroll
            for (int cc = 0; cc < 8; cc++) wv[cc] = sW[k * 128 + tc + 16 * cc];
#pragma unroll
            for (int r = 0; r < 4; r++)
#pragma unroll
                for (int cc = 0; cc < 8; cc++) acc[r][cc] += zr[r] * wv[cc];
        }
    }

#pragma unroll
    for (int r = 0; r < 4; r++) {
        int grow = row0 + r0 + r;
        if (grow >= N) continue;
#pragma unroll
        for (int cc = 0; cc < 8; cc++)
            H[(size_t)grow * 128 + tc + 16 * cc] = __float2bfloat16(acc[r][cc]);
    }
}

// t = (Z + skip) @ Wout   (Wout is [128,1])
template <typename ZT, typename XT>
__global__ void k_dot(const ZT* __restrict__ Z, const XT* __restrict__ skip,
                      const float* __restrict__ Wout, float* __restrict__ T, int N) {
    int w = threadIdx.x >> 6, lane = threadIdx.x & 63;
    int i = blockIdx.x * 4 + w;
    if (i >= N) return;
    float a = 0.f;
    for (int c = lane; c < 128; c += 64) {
        float v = IO<ZT>::ld(&Z[(size_t)i * 128 + c]) + IO<XT>::ld(&skip[(size_t)i * 128 + c]);
        a += v * Wout[c];
    }
    for (int o = 32; o > 0; o >>= 1) a += __shfl_down(a, o);
    if (lane == 0) T[i] = a;
}

// ---------------- batchnorm ----------------

template <typename ZT>
__global__ __launch_bounds__(256) void k_stats(const ZT* __restrict__ Y,
                                               float* __restrict__ st, int N) {
    int c = threadIdx.x & 127;
    int h = threadIdx.x >> 7;  // 0/1
    float s = 0.f, s2 = 0.f;
    for (int r = blockIdx.x * 2 + h; r < N; r += 512) {
        float v = IO<ZT>::ld(&Y[(size_t)r * 128 + c]);
        s += v;
        s2 += v * v;
    }
    __shared__ float ls[256], ls2[256];
    ls[threadIdx.x] = s;
    ls2[threadIdx.x] = s2;
    __syncthreads();
    if (h == 0) {
        s = ls[threadIdx.x] + ls[threadIdx.x + 128];
        s2 = ls2[threadIdx.x] + ls2[threadIdx.x + 128];
        atomicAdd(&st[c], s);
        atomicAdd(&st[128 + c], s2);
    }
}

__global__ void k_bnfin(const float* __restrict__ st, const float* __restrict__ gamma,
                        const float* __restrict__ beta, float* __restrict__ sc,
                        float* __restrict__ sh, int N) {
    int c = threadIdx.x;  // 128
    float inv_n = 1.0f / (float)N;
    float mean = st[c] * inv_n;
    float var = st[128 + c] * inv_n - mean * mean;
    float s = gamma[c] * rsqrtf(var + EPSV);
    sc[c] = s;
    sh[c] = beta[c] - mean * s;
}

template <typename ZT, typename XT>
__global__ void k_bnrelu(ZT* __restrict__ Y, const float* __restrict__ sc,
                         const float* __restrict__ sh, XT* __restrict__ save,
                         int total) {
    int idx = blockIdx.x * blockDim.x + threadIdx.x;
    if (idx >= total) return;
    int c = idx & 127;
    float v = IO<ZT>::ld(&Y[idx]) * sc[c] + sh[c];
    v = v > 0.f ? v : 0.f;
    IO<ZT>::st(&Y[idx], v);
    if (save) IO<XT>::st(&save[idx], v);
}

// ---------------- templated pipeline ----------------

template <typename ZT, typename XT>
static void run_all(const float* x, const int* src, const int* dst, const float* W0,
                    const float* Ws1, const float* g1, const float* b1,
                    const float* Ws2, const float* g2, const float* b2,
                    const float* Wout, float* out, char* ws, int N, int E,
                    hipStream_t stream) {
    char* p = ws;
    auto alloc = [&](size_t bytes) -> void* {
        void* r = (void*)p;
        p += (bytes + 255) & ~(size_t)255;
        return r;
    };
    int*   roff = (int*)alloc((size_t)(N + 1) * 4);
    float* dinv = (float*)alloc((size_t)N * 4);
    int*   col  = (int*)alloc((size_t)E * 4);
    float* val  = (float*)alloc((size_t)E * 4);
    int*   bsum = (int*)alloc(4096);
    float* st   = (float*)alloc(1024);
    float* sc   = (float*)alloc(512);
    float* sh   = (float*)alloc(512);
    size_t nz = (size_t)N * 128;
    ZT* zbuf = (ZT*)alloc(nz * sizeof(ZT));
    __hip_bfloat16* hb = (__hip_bfloat16*)alloc(nz * 2);
    XT* xs = (XT*)alloc((size_t)9 * nz * sizeof(XT));

    // lifetime-disjoint aliases (setup temporaries live only before layer 0)
    int* cnt    = (int*)zbuf;
    int* cursor = (int*)((char*)zbuf + (((size_t)N * 4 + 255) & ~(size_t)255));
    float* xa   = (float*)hb;                                              // [N,3], dead before hb first write
    float* tbuf = (float*)((char*)hb + (((size_t)N * 12 + 255) & ~(size_t)255));  // used after hb last read

    // --- CSR build ---
    hipMemsetAsync(cnt, 0, (size_t)N * 4, stream);
    k_count<<<(E + 255) / 256, 256, 0, stream>>>(dst, cnt, E);
    k_dinv<<<(N + 255) / 256, 256, 0, stream>>>(cnt, dinv, N);
    int B = (N + 255) / 256;
    k_scan1<<<B, 256, 0, stream>>>(cnt, bsum, N);
    k_scan2<<<1, 1024, 0, stream>>>(bsum, B);
    k_scan3<<<B, 256, 0, stream>>>(cnt, bsum, roff, cursor, N);
    k_scatter<<<(E + 255) / 256, 256, 0, stream>>>(src, dst, dinv, cursor, col, val, E);

    int total = N * 128;
    auto bn_stage = [&](const float* gamma, const float* beta, XT* save) {
        hipMemsetAsync(st, 0, 1024, stream);
        k_stats<ZT><<<256, 256, 0, stream>>>(zbuf, st, N);
        k_bnfin<<<1, 128, 0, stream>>>(st, gamma, beta, sc, sh, N);
        k_bnrelu<ZT, XT><<<(total + 255) / 256, 256, 0, stream>>>(zbuf, sc, sh, save, total);
    };

    // --- layer 0: (A@x)@W0, BN, ReLU ---
    k_spmm3<<<(N + 255) / 256, 256, 0, stream>>>(x, col, val, roff, dinv, xa, N);
    k_gemm3<ZT><<<(total + 255) / 256, 256, 0, stream>>>(xa, W0, zbuf, N);
    bn_stage(g1, b1, xs);  // save z_0 = xs[0]

    int gg = (N + GR - 1) / GR;

    // --- down: layers 1..9 ---
    for (int l = 1; l <= 9; l++) {
        k_gemm128<ZT, XT><<<gg, 256, 0, stream>>>(zbuf, (const XT*)nullptr,
                                                  Ws1 + (size_t)(l - 1) * 16384, hb, N);
        k_spmm128<ZT><<<N, 128, 0, stream>>>(hb, col, val, roff, dinv, zbuf, N);
        bn_stage(g1 + (size_t)l * 128, b1 + (size_t)l * 128,
                 (l <= 8) ? (xs + (size_t)l * nz) : (XT*)nullptr);
    }

    // --- up: 8 conv layers with skips ---
    for (int i = 0; i < 8; i++) {
        k_gemm128<ZT, XT><<<gg, 256, 0, stream>>>(zbuf, xs + (size_t)(8 - i) * nz,
                                                  Ws2 + (size_t)i * 16384, hb, N);
        k_spmm128<ZT><<<N, 128, 0, stream>>>(hb, col, val, roff, dinv, zbuf, N);
        bn_stage(g2 + (size_t)i * 128, b2 + (size_t)i * 128, (XT*)nullptr);
    }

    // --- output layer: sigmoid(A @ ((z + z0) @ Wout)) ---
    k_dot<ZT, XT><<<(N + 3) / 4, 256, 0, stream>>>(zbuf, xs, Wout, tbuf, N);
    k_spmm1<<<(N + 255) / 256, 256, 0, stream>>>(tbuf, col, val, roff, dinv, out, N);
}

// ---------------- launch ----------------

extern "C" void kernel_launch(void* const* d_in, const int* in_sizes, int n_in,
                              void* d_out, int out_size, void* d_ws, size_t ws_size,
                              hipStream_t stream) {
    const float* x    = (const float*)d_in[0];
    const int*   ei   = (const int*)d_in[1];
    const float* W0   = (const float*)d_in[2];
    const float* Ws1  = (const float*)d_in[3];
    const float* g1   = (const float*)d_in[4];
    const float* b1   = (const float*)d_in[5];
    const float* Ws2  = (const float*)d_in[6];
    const float* g2   = (const float*)d_in[7];
    const float* b2   = (const float*)d_in[8];
    const float* Wout = (const float*)d_in[9];
    float* out = (float*)d_out;

    int N = in_sizes[0] / 3;
    int E = in_sizes[1] / 2;
    const int* src = ei;
    const int* dst = ei + E;

    size_t nz = (size_t)N * 128;
    auto need = [&](size_t zb, size_t xb) -> size_t {
        size_t t = 0;
        auto add = [&](size_t b) { t += (b + 255) & ~(size_t)255; };
        add((size_t)(N + 1) * 4);  // roff
        add((size_t)N * 4);        // dinv
        add((size_t)E * 4);        // col
        add((size_t)E * 4);        // val
        add(4096); add(1024); add(512); add(512);  // bsum, st, sc, sh
        add(nz * zb);              // zbuf (hosts cnt+cursor early)
        add(nz * 2);               // hb16 (hosts xa+tbuf at the ends)
        add((size_t)9 * nz * xb);  // xs skip stack
        return t;
    };

    char* ws = (char*)d_ws;
    if (need(4, 2) <= ws_size)
        run_all<float, __hip_bfloat16>(x, src, dst, W0, Ws1, g1, b1, Ws2, g2, b2, Wout, out, ws, N, E, stream);
    else if (need(2, 2) <= ws_size)
        run_all<__hip_bfloat16, __hip_bfloat16>(x, src, dst, W0, Ws1, g1, b1, Ws2, g2, b2, Wout, out, ws, N, E, stream);
    else if (need(4, 1) <= ws_size)
        run_all<float, F8>(x, src, dst, W0, Ws1, g1, b1, Ws2, g2, b2, Wout, out, ws, N, E, stream);
    else
        run_all<__hip_bfloat16, F8>(x, src, dst, W0, Ws1, g1, b1, Ws2, g2, b2, Wout, out, ws, N, E, stream);
}

// Round 4
// 2964.315 us; speedup vs baseline: 2.0178x; 2.0178x over previous
//
#include <hip/hip_runtime.h>
#include <hip/hip_bf16.h>

#define EPSV 1e-5f

typedef unsigned int uint;
typedef unsigned short ushort;
typedef __attribute__((ext_vector_type(8))) __bf16 bf16x8;
typedef __attribute__((ext_vector_type(4))) float f32x4;

static __device__ __forceinline__ float bf2f(ushort u) {
    return __uint_as_float(((uint)u) << 16);
}
static __device__ __forceinline__ ushort f2bf(float f) {
    __hip_bfloat16 h = __float2bfloat16(f);
    return __builtin_bit_cast(ushort, h);
}

// ---------------- fp8 e4m3 codec (low-mem skip tier) ----------------

static __device__ __forceinline__ float e4m3_dec(unsigned char b) {
    int s = b >> 7, E = (b >> 3) & 15, m = b & 7;
    float v = (E == 0) ? (float)m * 0.001953125f
                       : (float)(8 + m) * 0.125f * exp2f((float)(E - 7));
    return s ? -v : v;
}
static __device__ __forceinline__ unsigned char e4m3_enc(float f) {
    unsigned su = (__float_as_uint(f) >> 24) & 0x80u;
    float a = fabsf(f);
    if (!(a < 448.f)) return (unsigned char)(su | 0x7E);
    if (a < 0.015625f) {
        int m = (int)rintf(a * 512.f);
        return (unsigned char)(su | (m >= 8 ? 0x08 : m));
    }
    int e;
    frexpf(a, &e);
    int E = e - 1 + 7;
    float mant = a * exp2f((float)(1 - e)) - 1.0f;
    int mi = (int)rintf(mant * 8.f);
    if (mi >= 8) { mi = 0; E++; }
    if (E >= 16) return (unsigned char)(su | 0x7E);
    if (E == 15 && mi == 7) mi = 6;
    return (unsigned char)(su | (E << 3) | mi);
}

// ---------------- storage traits ----------------

template <typename T> struct IOV;
template <> struct IOV<float> {
    static __device__ __forceinline__ float2 ld2(const float* p) { return *(const float2*)p; }
    static __device__ __forceinline__ void st2(float* p, float a, float b) {
        *(float2*)p = make_float2(a, b);
    }
    static __device__ __forceinline__ void ld8(const float* p, float* v) {
        float4 a = ((const float4*)p)[0], b = ((const float4*)p)[1];
        v[0] = a.x; v[1] = a.y; v[2] = a.z; v[3] = a.w;
        v[4] = b.x; v[5] = b.y; v[6] = b.z; v[7] = b.w;
    }
    static __device__ __forceinline__ void st8(float* p, const float* v) {
        ((float4*)p)[0] = make_float4(v[0], v[1], v[2], v[3]);
        ((float4*)p)[1] = make_float4(v[4], v[5], v[6], v[7]);
    }
};
template <> struct IOV<ushort> {  // bf16 bits
    static __device__ __forceinline__ float2 ld2(const ushort* p) {
        uint u = *(const uint*)p;
        return make_float2(bf2f((ushort)u), bf2f((ushort)(u >> 16)));
    }
    static __device__ __forceinline__ void st2(ushort* p, float a, float b) {
        *(uint*)p = (uint)f2bf(a) | ((uint)f2bf(b) << 16);
    }
    static __device__ __forceinline__ void ld8(const ushort* p, float* v) {
        uint4 u = *(const uint4*)p;
        v[0] = bf2f((ushort)u.x); v[1] = bf2f((ushort)(u.x >> 16));
        v[2] = bf2f((ushort)u.y); v[3] = bf2f((ushort)(u.y >> 16));
        v[4] = bf2f((ushort)u.z); v[5] = bf2f((ushort)(u.z >> 16));
        v[6] = bf2f((ushort)u.w); v[7] = bf2f((ushort)(u.w >> 16));
    }
    static __device__ __forceinline__ void st8(ushort* p, const float* v) {
        uint4 u;
        u.x = (uint)f2bf(v[0]) | ((uint)f2bf(v[1]) << 16);
        u.y = (uint)f2bf(v[2]) | ((uint)f2bf(v[3]) << 16);
        u.z = (uint)f2bf(v[4]) | ((uint)f2bf(v[5]) << 16);
        u.w = (uint)f2bf(v[6]) | ((uint)f2bf(v[7]) << 16);
        *(uint4*)p = u;
    }
};
template <> struct IOV<unsigned char> {  // fp8 e4m3
    static __device__ __forceinline__ float2 ld2(const unsigned char* p) {
        ushort u = *(const ushort*)p;
        return make_float2(e4m3_dec((unsigned char)u), e4m3_dec((unsigned char)(u >> 8)));
    }
    static __device__ __forceinline__ void st2(unsigned char* p, float a, float b) {
        *(ushort*)p = (ushort)e4m3_enc(a) | ((ushort)e4m3_enc(b) << 8);
    }
    static __device__ __forceinline__ void ld8(const unsigned char* p, float* v) {
        uint2 u = *(const uint2*)p;
#pragma unroll
        for (int j = 0; j < 4; j++) v[j] = e4m3_dec((unsigned char)(u.x >> (8 * j)));
#pragma unroll
        for (int j = 0; j < 4; j++) v[4 + j] = e4m3_dec((unsigned char)(u.y >> (8 * j)));
    }
    static __device__ __forceinline__ void st8(unsigned char* p, const float* v) {
        uint2 u = {0, 0};
#pragma unroll
        for (int j = 0; j < 4; j++) u.x |= (uint)e4m3_enc(v[j]) << (8 * j);
#pragma unroll
        for (int j = 0; j < 4; j++) u.y |= (uint)e4m3_enc(v[4 + j]) << (8 * j);
        *(uint2*)p = u;
    }
};

// ---------------- graph setup ----------------

__global__ void k_count(const int* __restrict__ dst, int* __restrict__ cnt, int E) {
    int e = blockIdx.x * blockDim.x + threadIdx.x;
    if (e < E) atomicAdd(&cnt[dst[e]], 1);
}

__global__ void k_dinv(const int* __restrict__ cnt, float* __restrict__ dinv, int N) {
    int i = blockIdx.x * blockDim.x + threadIdx.x;
    if (i < N) dinv[i] = rsqrtf((float)(cnt[i] + 1));
}

__global__ void k_scan1(const int* __restrict__ cnt, int* __restrict__ bsum, int N) {
    __shared__ int s[256];
    int i = blockIdx.x * 256 + threadIdx.x;
    s[threadIdx.x] = (i < N) ? cnt[i] : 0;
    __syncthreads();
    for (int o = 128; o > 0; o >>= 1) {
        if (threadIdx.x < o) s[threadIdx.x] += s[threadIdx.x + o];
        __syncthreads();
    }
    if (threadIdx.x == 0) bsum[blockIdx.x] = s[0];
}

__global__ void k_scan2(int* __restrict__ bsum, int B) {
    __shared__ int s[1024];
    int t = threadIdx.x;
    int orig = (t < B) ? bsum[t] : 0;
    s[t] = orig;
    __syncthreads();
    for (int o = 1; o < 1024; o <<= 1) {
        int v = (t >= o) ? s[t - o] : 0;
        __syncthreads();
        s[t] += v;
        __syncthreads();
    }
    if (t < B) bsum[t] = s[t] - orig;
}

__global__ void k_scan3(const int* __restrict__ cnt, const int* __restrict__ bsum,
                        int* __restrict__ roff, int* __restrict__ cursor, int N) {
    __shared__ int s[256];
    int i = blockIdx.x * 256 + threadIdx.x;
    int v = (i < N) ? cnt[i] : 0;
    s[threadIdx.x] = v;
    __syncthreads();
    for (int o = 1; o < 256; o <<= 1) {
        int u = (threadIdx.x >= o) ? s[threadIdx.x - o] : 0;
        __syncthreads();
        s[threadIdx.x] += u;
        __syncthreads();
    }
    if (i < N) {
        int off = bsum[blockIdx.x] + s[threadIdx.x] - v;
        roff[i] = off;
        cursor[i] = off;
        if (i == N - 1) roff[N] = off + v;
    }
}

__global__ void k_scatter(const int* __restrict__ src, const int* __restrict__ dst,
                          const float* __restrict__ dinv, int* __restrict__ cursor,
                          int* __restrict__ col, float* __restrict__ val, int E) {
    int e = blockIdx.x * blockDim.x + threadIdx.x;
    if (e < E) {
        int s = src[e], d = dst[e];
        int p = atomicAdd(&cursor[d], 1);
        col[p] = s;
        val[p] = dinv[s] * dinv[d];
    }
}

// ---------------- sparse ops ----------------

__global__ void k_spmm3(const float* __restrict__ X, const int* __restrict__ col,
                        const float* __restrict__ val, const int* __restrict__ roff,
                        const float* __restrict__ dinv, float* __restrict__ XA, int N) {
    int i = blockIdx.x * blockDim.x + threadIdx.x;
    if (i >= N) return;
    float di = dinv[i];
    float w0 = di * di;
    float a0 = X[(size_t)i * 3 + 0] * w0;
    float a1 = X[(size_t)i * 3 + 1] * w0;
    float a2 = X[(size_t)i * 3 + 2] * w0;
    int je = roff[i + 1];
    for (int j = roff[i]; j < je; j++) {
        int s = col[j];
        float w = val[j];
        a0 += X[(size_t)s * 3 + 0] * w;
        a1 += X[(size_t)s * 3 + 1] * w;
        a2 += X[(size_t)s * 3 + 2] * w;
    }
    XA[(size_t)i * 3 + 0] = a0;
    XA[(size_t)i * 3 + 1] = a1;
    XA[(size_t)i * 3 + 2] = a2;
}

// Z(pre-BN) = A @ H (H bf16): wave-per-row, bf16x2/lane, 4-way unrolled gathers
template <typename ZT>
__global__ __launch_bounds__(256) void k_spmm128(
    const ushort* __restrict__ H, const int* __restrict__ col,
    const float* __restrict__ val, const int* __restrict__ roff,
    const float* __restrict__ dinv, ZT* __restrict__ Y, int N) {
    int i = blockIdx.x * 4 + (threadIdx.x >> 6);
    if (i >= N) return;
    int lane = threadIdx.x & 63;
    const uint* Hu = (const uint*)H;
    float di = dinv[i];
    float ws = di * di;
    uint u = Hu[(size_t)i * 64 + lane];
    float a0 = bf2f((ushort)u) * ws, a1 = bf2f((ushort)(u >> 16)) * ws;
    int j = roff[i], je = roff[i + 1];
    for (; j + 4 <= je; j += 4) {
        int s0 = col[j], s1 = col[j + 1], s2 = col[j + 2], s3 = col[j + 3];
        float w0 = val[j], w1 = val[j + 1], w2 = val[j + 2], w3 = val[j + 3];
        uint u0 = Hu[(size_t)s0 * 64 + lane];
        uint u1 = Hu[(size_t)s1 * 64 + lane];
        uint u2 = Hu[(size_t)s2 * 64 + lane];
        uint u3 = Hu[(size_t)s3 * 64 + lane];
        a0 += bf2f((ushort)u0) * w0 + bf2f((ushort)u1) * w1 +
              bf2f((ushort)u2) * w2 + bf2f((ushort)u3) * w3;
        a1 += bf2f((ushort)(u0 >> 16)) * w0 + bf2f((ushort)(u1 >> 16)) * w1 +
              bf2f((ushort)(u2 >> 16)) * w2 + bf2f((ushort)(u3 >> 16)) * w3;
    }
    for (; j < je; j++) {
        int s = col[j];
        float w = val[j];
        uint uu = Hu[(size_t)s * 64 + lane];
        a0 += bf2f((ushort)uu) * w;
        a1 += bf2f((ushort)(uu >> 16)) * w;
    }
    IOV<ZT>::st2(&Y[(size_t)i * 128 + 2 * lane], a0, a1);
}

__global__ void k_spmm1(const float* __restrict__ T, const int* __restrict__ col,
                        const float* __restrict__ val, const int* __restrict__ roff,
                        const float* __restrict__ dinv, float* __restrict__ out, int N) {
    int i = blockIdx.x * blockDim.x + threadIdx.x;
    if (i >= N) return;
    float di = dinv[i];
    float a = T[i] * di * di;
    int je = roff[i + 1];
    for (int j = roff[i]; j < je; j++) a += T[col[j]] * val[j];
    out[i] = 1.0f / (1.0f + expf(-a));
}

// ---------------- per-channel stats (sum, sumsq) ----------------

template <typename ZT>
__global__ __launch_bounds__(256) void k_stats(const ZT* __restrict__ Z,
                                               float* __restrict__ st, int N) {
    int lane = threadIdx.x & 63, rg = threadIdx.x >> 6;
    float s0 = 0.f, s1 = 0.f, q0 = 0.f, q1 = 0.f;
    for (int r = blockIdx.x * 4 + rg; r < N; r += gridDim.x * 4) {
        float2 v = IOV<ZT>::ld2(&Z[(size_t)r * 128 + 2 * lane]);
        s0 += v.x; q0 += v.x * v.x;
        s1 += v.y; q1 += v.y * v.y;
    }
    __shared__ float ls[4][64][4];
    ls[rg][lane][0] = s0; ls[rg][lane][1] = s1;
    ls[rg][lane][2] = q0; ls[rg][lane][3] = q1;
    __syncthreads();
    if (rg == 0) {
        for (int g = 1; g < 4; g++) {
            s0 += ls[g][lane][0]; s1 += ls[g][lane][1];
            q0 += ls[g][lane][2]; q1 += ls[g][lane][3];
        }
        atomicAdd(&st[2 * lane], s0);
        atomicAdd(&st[2 * lane + 1], s1);
        atomicAdd(&st[128 + 2 * lane], q0);
        atomicAdd(&st[129 + 2 * lane], q1);
    }
}

// ---------------- dense ops ----------------

// z(stage0, pre-BN) = (A@x) @ W0
template <typename ZT>
__global__ void k_gemm3(const float* __restrict__ XA, const float* __restrict__ W0,
                        ZT* __restrict__ Y, int N) {
    int idx = blockIdx.x * blockDim.x + threadIdx.x;
    if (idx >= N * 64) return;
    int i = idx >> 6, c0 = (idx & 63) * 2;
    float x0 = XA[(size_t)i * 3], x1 = XA[(size_t)i * 3 + 1], x2 = XA[(size_t)i * 3 + 2];
    float y0 = x0 * W0[c0] + x1 * W0[128 + c0] + x2 * W0[256 + c0];
    float y1 = x0 * W0[c0 + 1] + x1 * W0[128 + c0 + 1] + x2 * W0[256 + c0 + 1];
    IOV<ZT>::st2(&Y[(size_t)i * 128 + c0], y0, y1);
}

// H(bf16) = [ReLU(BN(Z)) + skip_in] @ W  (MFMA bf16, A and W hi/lo split).
// Optionally saves ReLU(BN(Z)) (post-act!) to skip_out. BN affine from st in-kernel.
template <typename ZT, typename SKT>
__global__ __launch_bounds__(256) void k_gemm_mfma(
    const ZT* __restrict__ Z, const SKT* __restrict__ skip_in, SKT* __restrict__ skip_out,
    const float* __restrict__ stz, const float* __restrict__ gz, const float* __restrict__ bz,
    const float* __restrict__ W, ushort* __restrict__ H, float invN, int N) {
    __shared__ ushort sW[128 * 136];
    __shared__ float sA[256];
    int tid = threadIdx.x;

    if (tid < 128) {
        float m = stz[tid] * invN;
        float var = stz[128 + tid] * invN - m * m;
        float s = gz[tid] * rsqrtf(var + EPSV);
        sA[tid] = s;
        sA[128 + tid] = bz[tid] - m * s;
    }
    // stage W hi (bf16), layout W^T[n][k], stride 136
    for (int t = tid; t < 16384; t += 256) {
        int k = t >> 7, n = t & 127;
        sW[n * 136 + k] = f2bf(W[t]);
    }
    __syncthreads();

    int wave = tid >> 6, lane = tid & 63, l15 = lane & 15, quad = lane >> 4;
    int row = blockIdx.x * 64 + wave * 16 + l15;
    size_t rowc = (size_t)(row < N ? row : N - 1);

    bf16x8 ahi[4], alo[4];
#pragma unroll
    for (int kc = 0; kc < 4; kc++) {
        int c0 = kc * 32 + quad * 8;
        float v[8];
        IOV<ZT>::ld8(&Z[rowc * 128 + c0], v);
        float av[8];
#pragma unroll
        for (int jj = 0; jj < 8; jj++) {
            float t = v[jj] * sA[c0 + jj] + sA[128 + c0 + jj];
            av[jj] = fmaxf(t, 0.f);
        }
        if (skip_out && row < N) IOV<SKT>::st8(&skip_out[rowc * 128 + c0], av);
        if (skip_in) {
            float w2[8];
            IOV<SKT>::ld8(&skip_in[rowc * 128 + c0], w2);
#pragma unroll
            for (int jj = 0; jj < 8; jj++) av[jj] += w2[jj];
        }
        bf16x8 fh, fl;
#pragma unroll
        for (int jj = 0; jj < 8; jj++) {
            __bf16 h = (__bf16)av[jj];
            fh[jj] = h;
            fl[jj] = (__bf16)(av[jj] - (float)h);
        }
        ahi[kc] = fh;
        alo[kc] = fl;
    }

    f32x4 acc[8];
#pragma unroll
    for (int ct = 0; ct < 8; ct++) {
        f32x4 z0 = {0.f, 0.f, 0.f, 0.f};
        acc[ct] = z0;
    }

    // pass 1: (Ahi + Alo) * Whi
#pragma unroll
    for (int ct = 0; ct < 8; ct++) {
        int nb = ct * 16 + l15;
#pragma unroll
        for (int kc = 0; kc < 4; kc++) {
            bf16x8 b = *(const bf16x8*)&sW[nb * 136 + kc * 32 + quad * 8];
            acc[ct] = __builtin_amdgcn_mfma_f32_16x16x32_bf16(ahi[kc], b, acc[ct], 0, 0, 0);
            acc[ct] = __builtin_amdgcn_mfma_f32_16x16x32_bf16(alo[kc], b, acc[ct], 0, 0, 0);
        }
    }
    __syncthreads();
    // stage W lo (residual)
    for (int t = tid; t < 16384; t += 256) {
        int k = t >> 7, n = t & 127;
        float w = W[t];
        float hi = bf2f(f2bf(w));
        sW[n * 136 + k] = f2bf(w - hi);
    }
    __syncthreads();
    // pass 2: Ahi * Wlo
#pragma unroll
    for (int ct = 0; ct < 8; ct++) {
        int nb = ct * 16 + l15;
#pragma unroll
        for (int kc = 0; kc < 4; kc++) {
            bf16x8 b = *(const bf16x8*)&sW[nb * 136 + kc * 32 + quad * 8];
            acc[ct] = __builtin_amdgcn_mfma_f32_16x16x32_bf16(ahi[kc], b, acc[ct], 0, 0, 0);
        }
    }
    __syncthreads();
    // epilogue: C layout col=lane&15, row=quad*4+reg -> LDS -> coalesced bf16 store
    ushort* sC = sW;
#pragma unroll
    for (int ct = 0; ct < 8; ct++)
#pragma unroll
        for (int reg = 0; reg < 4; reg++) {
            int r = wave * 16 + quad * 4 + reg;
            sC[r * 136 + ct * 16 + l15] = f2bf(acc[ct][reg]);
        }
    __syncthreads();
    for (int t = tid; t < 1024; t += 256) {
        int r = t >> 4, c4 = t & 15;
        int grow = blockIdx.x * 64 + r;
        if (grow < N)
            ((uint4*)(H + (size_t)grow * 128))[c4] = *(const uint4*)&sC[r * 136 + c4 * 8];
    }
}

// t = [ReLU(BN(Z)) + skip0(post-act)] @ Wout  (wave per row)
template <typename ZT, typename SKT>
__global__ __launch_bounds__(256) void k_dot(
    const ZT* __restrict__ Z, const SKT* __restrict__ S0,
    const float* __restrict__ stz, const float* __restrict__ gz, const float* __restrict__ bz,
    const float* __restrict__ Wout, float* __restrict__ T, float invN, int N) {
    int i = blockIdx.x * 4 + (threadIdx.x >> 6);
    if (i >= N) return;
    int lane = threadIdx.x & 63;
    int c0 = 2 * lane, c1 = c0 + 1;
    float2 z = IOV<ZT>::ld2(&Z[(size_t)i * 128 + c0]);
    float2 s = IOV<SKT>::ld2(&S0[(size_t)i * 128 + c0]);
    float m, var;
    m = stz[c0] * invN; var = stz[128 + c0] * invN - m * m;
    float az0 = gz[c0] * rsqrtf(var + EPSV), hz0 = bz[c0] - m * az0;
    m = stz[c1] * invN; var = stz[128 + c1] * invN - m * m;
    float az1 = gz[c1] * rsqrtf(var + EPSV), hz1 = bz[c1] - m * az1;
    float p0 = fmaxf(z.x * az0 + hz0, 0.f) + s.x;
    float p1 = fmaxf(z.y * az1 + hz1, 0.f) + s.y;
    float a = p0 * Wout[c0] + p1 * Wout[c1];
    for (int o = 32; o > 0; o >>= 1) a += __shfl_down(a, o);
    if (lane == 0) T[i] = a;
}

// ---------------- templated pipeline ----------------

template <typename ZT, typename SKT>
static void run_all(const float* x, const int* src, const int* dst, const float* W0,
                    const float* Ws1, const float* g1, const float* b1,
                    const float* Ws2, const float* g2, const float* b2,
                    const float* Wout, float* out, char* ws, int N, int E,
                    hipStream_t stream) {
    char* p = ws;
    auto alloc = [&](size_t bytes) -> void* {
        void* r = (void*)p;
        p += (bytes + 255) & ~(size_t)255;
        return r;
    };
    int*   roff   = (int*)alloc((size_t)(N + 1) * 4);
    float* dinv   = (float*)alloc((size_t)N * 4);
    int*   col    = (int*)alloc((size_t)E * 4);
    float* val    = (float*)alloc((size_t)E * 4);
    int*   bsum   = (int*)alloc(4096);
    float* st_all = (float*)alloc(18 * 256 * 4);
    size_t nz = (size_t)N * 128;
    ushort* hb = (ushort*)alloc(nz * 2);             // bf16 message buffer
    ZT* zb = (ZT*)alloc(nz * sizeof(ZT));            // single pre-BN z buffer
    SKT* skips = (SKT*)alloc((size_t)9 * nz * sizeof(SKT));  // post-act skip saves
    auto skip = [&](int s) { return skips + (size_t)s * nz; };

    // lifetime-disjoint aliases: skip[8] first written at down layer 9 (after CSR)
    int* cnt    = (int*)skip(8);
    int* cursor = (int*)((char*)skip(8) + (((size_t)N * 4 + 255) & ~(size_t)255));
    float* xa   = (float*)hb;   // [N,3]; dead before first hb write
    float* tbuf = (float*)hb;   // [N]; written after last hb read

    float invN = 1.0f / (float)N;
    // stage s BN params: s<=9 -> g1[s]; s>=10 -> g2[s-10]
    auto gb = [&](int stage, const float** g, const float** b) {
        if (stage <= 9) { *g = g1 + (size_t)stage * 128; *b = b1 + (size_t)stage * 128; }
        else { *g = g2 + (size_t)(stage - 10) * 128; *b = b2 + (size_t)(stage - 10) * 128; }
    };

    // --- CSR build ---
    hipMemsetAsync(st_all, 0, 18 * 256 * 4, stream);
    hipMemsetAsync(cnt, 0, (size_t)N * 4, stream);
    k_count<<<(E + 255) / 256, 256, 0, stream>>>(dst, cnt, E);
    k_dinv<<<(N + 255) / 256, 256, 0, stream>>>(cnt, dinv, N);
    int B = (N + 255) / 256;
    k_scan1<<<B, 256, 0, stream>>>(cnt, bsum, N);
    k_scan2<<<1, 1024, 0, stream>>>(bsum, B);
    k_scan3<<<B, 256, 0, stream>>>(cnt, bsum, roff, cursor, N);
    k_scatter<<<(E + 255) / 256, 256, 0, stream>>>(src, dst, dinv, cursor, col, val, E);

    int gg = (N + 63) / 64;
    int gs4 = (N + 3) / 4;

    // --- layer 0: z = (A@x)@W0 (pre-BN), stats stage 0 ---
    k_spmm3<<<(N + 255) / 256, 256, 0, stream>>>(x, col, val, roff, dinv, xa, N);
    k_gemm3<ZT><<<(N * 64 + 255) / 256, 256, 0, stream>>>(xa, W0, zb, N);
    k_stats<ZT><<<512, 256, 0, stream>>>(zb, st_all, N);

    // --- down layers 1..9: GEMM saves act(stage l-1) to skip[l-1] ---
    for (int l = 1; l <= 9; l++) {
        const float *gzp, *bzp;
        gb(l - 1, &gzp, &bzp);
        k_gemm_mfma<ZT, SKT><<<gg, 256, 0, stream>>>(
            zb, (const SKT*)nullptr, skip(l - 1), st_all + (size_t)(l - 1) * 256, gzp, bzp,
            Ws1 + (size_t)(l - 1) * 16384, hb, invN, N);
        k_spmm128<ZT><<<gs4, 256, 0, stream>>>(hb, col, val, roff, dinv, zb, N);
        k_stats<ZT><<<512, 256, 0, stream>>>(zb, st_all + (size_t)l * 256, N);
    }

    // --- up layers 0..7 (skip-add, post-act skips) ---
    for (int i = 0; i < 8; i++) {
        int zs = 9 + i;
        const float *gzp, *bzp;
        gb(zs, &gzp, &bzp);
        k_gemm_mfma<ZT, SKT><<<gg, 256, 0, stream>>>(
            zb, skip(8 - i), (SKT*)nullptr, st_all + (size_t)zs * 256, gzp, bzp,
            Ws2 + (size_t)i * 16384, hb, invN, N);
        k_spmm128<ZT><<<gs4, 256, 0, stream>>>(hb, col, val, roff, dinv, zb, N);
        k_stats<ZT><<<512, 256, 0, stream>>>(zb, st_all + (size_t)(10 + i) * 256, N);
    }

    // --- output: sigmoid(A @ ([act17(z) + skip0] @ Wout)) ---
    const float *gzp, *bzp;
    gb(17, &gzp, &bzp);
    k_dot<ZT, SKT><<<gs4, 256, 0, stream>>>(zb, skip(0), st_all + 17 * 256, gzp, bzp,
                                            Wout, tbuf, invN, N);
    k_spmm1<<<(N + 255) / 256, 256, 0, stream>>>(tbuf, col, val, roff, dinv, out, N);
}

// ---------------- launch ----------------

extern "C" void kernel_launch(void* const* d_in, const int* in_sizes, int n_in,
                              void* d_out, int out_size, void* d_ws, size_t ws_size,
                              hipStream_t stream) {
    const float* x    = (const float*)d_in[0];
    const int*   ei   = (const int*)d_in[1];
    const float* W0   = (const float*)d_in[2];
    const float* Ws1  = (const float*)d_in[3];
    const float* g1   = (const float*)d_in[4];
    const float* b1   = (const float*)d_in[5];
    const float* Ws2  = (const float*)d_in[6];
    const float* g2   = (const float*)d_in[7];
    const float* b2   = (const float*)d_in[8];
    const float* Wout = (const float*)d_in[9];
    float* out = (float*)d_out;

    int N = in_sizes[0] / 3;
    int E = in_sizes[1] / 2;
    const int* src = ei;
    const int* dst = ei + E;

    size_t nz = (size_t)N * 128;
    auto need = [&](size_t zbytes, size_t skbytes) -> size_t {
        size_t t = 0;
        auto add = [&](size_t b) { t += (b + 255) & ~(size_t)255; };
        add((size_t)(N + 1) * 4);
        add((size_t)N * 4);
        add((size_t)E * 4);
        add((size_t)E * 4);
        add(4096);
        add(18 * 256 * 4);
        add(nz * 2);                    // h
        add(nz * zbytes);               // z
        add((size_t)9 * nz * skbytes);  // skips
        return t;
    };

    char* ws = (char*)d_ws;
    if (need(4, 2) <= ws_size)          // fp32 z, bf16 skips (~322 MB)
        run_all<float, ushort>(x, src, dst, W0, Ws1, g1, b1, Ws2, g2, b2, Wout, out, ws, N, E, stream);
    else if (need(4, 1) <= ws_size)     // fp32 z, fp8 skips (~206 MB)
        run_all<float, unsigned char>(x, src, dst, W0, Ws1, g1, b1, Ws2, g2, b2, Wout, out, ws, N, E, stream);
    else                                // bf16 z, fp8 skips (~180 MB)
        run_all<ushort, unsigned char>(x, src, dst, W0, Ws1, g1, b1, Ws2, g2, b2, Wout, out, ws, N, E, stream);
}